// Round 1
// baseline (446.356 us; speedup 1.0000x reference)
//
#include <hip/hip_runtime.h>
#include <stdint.h>

// BitLinear: out[b,o] = 4096 - 2*popcount(A[b] ^ W[o]) + bias[o]
// B=8192, O=4096, K=4096 bits. Inputs packed 8 bits per int32 (P=512 words/row).
//
// Stage 1: repack 4 bytes -> 1 dense uint32  (A: 8192x128, W: 4096x128) into d_ws.
// Stage 2: VALU popcount-GEMM, 128x128 block tile, 8x8 per-thread register tile,
//          LDS-staged K chunks of 32 words, xor-swizzled columns for bank-conflict-free
//          ds_read_b128 fragment loads.

#define BATCH 8192
#define OUTF  4096
#define KW    128   // dense uint32 words per row (4096 bits)
#define BM    128
#define BN    128
#define BK    32    // K-chunk in words
#define TM    8
#define TN    8

// physical column swizzle: keeps 16B alignment (operates on 4-word groups)
#define SWZ(m, kk) ((kk) ^ ((((m) >> 3) & 7) << 2))

__global__ __launch_bounds__(256) void repack_kernel(const int* __restrict__ src,
                                                     uint32_t* __restrict__ dst,
                                                     int nwords) {
    int idx = blockIdx.x * 256 + threadIdx.x;
    if (idx >= nwords) return;
    int4 v = ((const int4*)src)[idx];
    dst[idx] = (uint32_t)(v.x & 0xFF)
             | ((uint32_t)(v.y & 0xFF) << 8)
             | ((uint32_t)(v.z & 0xFF) << 16)
             | ((uint32_t)(v.w & 0xFF) << 24);
}

__global__ __launch_bounds__(256) void bitgemm_kernel(const uint32_t* __restrict__ A,
                                                      const uint32_t* __restrict__ W,
                                                      const float* __restrict__ bias,
                                                      float* __restrict__ out) {
    __shared__ __attribute__((aligned(16))) uint32_t As[BM][BK];
    __shared__ __attribute__((aligned(16))) uint32_t Ws[BN][BK];

    const int tid = threadIdx.x;
    const int ti = tid >> 4;   // 0..15, row group (TM rows each)
    const int tj = tid & 15;   // 0..15, col group (TN cols each)
    const int m0 = blockIdx.y * BM;
    const int n0 = blockIdx.x * BN;

    uint32_t acc[TM][TN];
#pragma unroll
    for (int i = 0; i < TM; ++i)
#pragma unroll
        for (int j = 0; j < TN; ++j) acc[i][j] = 0u;

#pragma unroll 1
    for (int kc = 0; kc < KW; kc += BK) {
        // Stage A-tile (128x32 words = 1024 uint4) and W-tile: 4 uint4 each per thread.
#pragma unroll
        for (int it = 0; it < 4; ++it) {
            int u  = tid + it * 256;      // uint4 index within tile (0..1023)
            int m  = u >> 3;              // 8 uint4 per 32-word row
            int kk = (u & 7) << 2;
            uint4 va = *(const uint4*)&A[(m0 + m) * KW + kc + kk];
            *(uint4*)&As[m][SWZ(m, kk)] = va;
            uint4 vw = *(const uint4*)&W[(n0 + m) * KW + kc + kk];
            *(uint4*)&Ws[m][SWZ(m, kk)] = vw;
        }
        __syncthreads();

#pragma unroll 2
        for (int kk = 0; kk < BK; kk += 4) {
            uint4 av[TM], wv[TN];
#pragma unroll
            for (int i = 0; i < TM; ++i) {
                int m = ti * TM + i;
                av[i] = *(const uint4*)&As[m][SWZ(m, kk)];
            }
#pragma unroll
            for (int j = 0; j < TN; ++j) {
                int n = tj * TN + j;
                wv[j] = *(const uint4*)&Ws[n][SWZ(n, kk)];
            }
#pragma unroll
            for (int i = 0; i < TM; ++i)
#pragma unroll
                for (int j = 0; j < TN; ++j) {
                    // v_xor_b32 + v_bcnt_u32_b32 (popcount with fused add)
                    acc[i][j] += __popc(av[i].x ^ wv[j].x);
                    acc[i][j] += __popc(av[i].y ^ wv[j].y);
                    acc[i][j] += __popc(av[i].z ^ wv[j].z);
                    acc[i][j] += __popc(av[i].w ^ wv[j].w);
                }
        }
        __syncthreads();
    }

    // Epilogue: out = 4096 - 2*acc + bias, float4-vectorized stores.
    float bj[TN];
#pragma unroll
    for (int j = 0; j < TN; ++j) bj[j] = bias[n0 + tj * TN + j];

#pragma unroll
    for (int i = 0; i < TM; ++i) {
        int row = m0 + ti * TM + i;
        float* op = out + (size_t)row * OUTF + n0 + tj * TN;
        float4 r0, r1;
        r0.x = (float)(4096 - 2 * (int)acc[i][0]) + bj[0];
        r0.y = (float)(4096 - 2 * (int)acc[i][1]) + bj[1];
        r0.z = (float)(4096 - 2 * (int)acc[i][2]) + bj[2];
        r0.w = (float)(4096 - 2 * (int)acc[i][3]) + bj[3];
        r1.x = (float)(4096 - 2 * (int)acc[i][4]) + bj[4];
        r1.y = (float)(4096 - 2 * (int)acc[i][5]) + bj[5];
        r1.z = (float)(4096 - 2 * (int)acc[i][6]) + bj[6];
        r1.w = (float)(4096 - 2 * (int)acc[i][7]) + bj[7];
        *(float4*)op       = r0;
        *(float4*)(op + 4) = r1;
    }
}

extern "C" void kernel_launch(void* const* d_in, const int* in_sizes, int n_in,
                              void* d_out, int out_size, void* d_ws, size_t ws_size,
                              hipStream_t stream) {
    const int*   a_packed = (const int*)d_in[0];    // [8192, 512] int32 (bytes)
    const int*   w_packed = (const int*)d_in[1];    // [4096, 512] int32 (bytes)
    const float* bias     = (const float*)d_in[2];  // [4096] f32
    float*       out      = (float*)d_out;          // [8192, 4096] f32

    uint32_t* Ad = (uint32_t*)d_ws;                 // 8192*128 u32 = 4 MiB
    uint32_t* Wd = Ad + BATCH * KW;                 // 4096*128 u32 = 2 MiB

    const int nA = BATCH * KW;   // 1048576
    const int nW = OUTF * KW;    //  524288
    repack_kernel<<<nA / 256, 256, 0, stream>>>(a_packed, Ad, nA);
    repack_kernel<<<nW / 256, 256, 0, stream>>>(w_packed, Wd, nW);

    dim3 grid(OUTF / BN, BATCH / BM);   // (32, 64)
    bitgemm_kernel<<<grid, 256, 0, stream>>>(Ad, Wd, bias, out);
}

// Round 2
// 439.503 us; speedup vs baseline: 1.0156x; 1.0156x over previous
//
#include <hip/hip_runtime.h>
#include <stdint.h>

// BitLinear via i8 MFMA: unpack bits -> +/-1 int8, then C = A (8192x4096) * W^T (4096x4096)
// with v_mfma_i32_32x32x32_i8, + bias.
//
// GEMM: block tile 128(M) x 256(N), 256 threads (4 waves), wave-tile 64x128.
// BK = 128 k-bytes per iteration. LDS staged in MFMA-FRAGMENT-BLOCK order:
// each 1 KB LDS block == one wave fragment (lane-major, 16 B/lane), produced
// directly by global_load_lds (dest = base + lane*16). Fragment ds_read_b128
// are then perfectly linear (conflict-free) with immediate offsets.

typedef int v4i  __attribute__((ext_vector_type(4)));
typedef int v16i __attribute__((ext_vector_type(16)));

#define BATCH 8192
#define OUTF  4096
#define KDIM  4096
#define BM    128
#define BN    256
#define BKB   128   // K bytes per iteration

// ---------------- unpack: packed byte-per-int32 -> +/-1 int8 ----------------
__device__ inline void expand8(uint32_t x, uint32_t& lo, uint32_t& hi) {
    lo = 0u; hi = 0u;
#pragma unroll
    for (int j = 0; j < 4; ++j) {
        lo |= ((((x >> j)       & 1u) * 2u - 1u) & 0xFFu) << (8 * j);
        hi |= ((((x >> (j + 4)) & 1u) * 2u - 1u) & 0xFFu) << (8 * j);
    }
}

__global__ __launch_bounds__(256) void unpack_kernel(const int* __restrict__ a_packed,
                                                     const int* __restrict__ w_packed,
                                                     char* __restrict__ Ai8,
                                                     char* __restrict__ Wi8) {
    const int NA2 = BATCH * 512 / 2;   // int32 pairs in A
    const int NW2 = OUTF  * 512 / 2;
    int t = blockIdx.x * 256 + threadIdx.x;
    const int2* src;
    int4* dst;
    int p;
    if (t < NA2) { src = (const int2*)a_packed; dst = (int4*)Ai8; p = t; }
    else         { p = t - NA2; if (p >= NW2) return;
                   src = (const int2*)w_packed; dst = (int4*)Wi8; }
    int2 v = src[p];
    uint32_t l0, h0, l1, h1;
    expand8((uint32_t)v.x, l0, h0);
    expand8((uint32_t)v.y, l1, h1);
    int4 o; o.x = (int)l0; o.y = (int)h0; o.z = (int)l1; o.w = (int)h1;
    dst[p] = o;
}

// ---------------- i8 MFMA GEMM ----------------
__global__ __launch_bounds__(256) void bitgemm_mfma(const char* __restrict__ A,
                                                    const char* __restrict__ W,
                                                    const float* __restrict__ bias,
                                                    float* __restrict__ out) {
    // 48 fragment blocks of 1 KB: A blocks 0..15 (mt 0..3 x s 0..3),
    // W blocks 16..47 (nt 0..7 x s 0..3).
    __shared__ __attribute__((aligned(16))) char lds[48 * 1024];

    const int tid  = threadIdx.x;
    const int lane = tid & 63;
    const int w    = __builtin_amdgcn_readfirstlane(tid >> 6);
    const int m0   = blockIdx.y * BM;
    const int n0   = blockIdx.x * BN;

    // per-lane source offset inside a fragment block: row = lane&31, koff = (lane>>5)*16
    const int laneOff = (lane & 31) * KDIM + (lane >> 5) * 16;
    const char* pA = A + (size_t)m0 * KDIM + laneOff;
    const char* pW = W + (size_t)n0 * KDIM + laneOff;

    const int mtb = (w & 1) * 2;   // wave's A tile base (of 4)
    const int ntb = (w >> 1) * 4;  // wave's W tile base (of 8)

    v16i acc[2][4];
#pragma unroll
    for (int mt = 0; mt < 2; ++mt)
#pragma unroll
        for (int nt = 0; nt < 4; ++nt)
#pragma unroll
            for (int r = 0; r < 16; ++r) acc[mt][nt][r] = 0;

    // fragment base pointers (per-thread: lane*16 plus wave-tile offset; all
    // loop offsets become compile-time immediates)
    const v4i* fA = (const v4i*)(lds) + mtb * 4 * 64 + lane;
    const v4i* fW = (const v4i*)(lds + 16 * 1024) + ntb * 4 * 64 + lane;

#pragma unroll 1
    for (int kc = 0; kc < KDIM; kc += BKB) {
        // stage 48 x 1KB fragment blocks; wave w stages blocks w*12 .. w*12+11
#pragma unroll
        for (int j = 0; j < 12; ++j) {
            int bi = w * 12 + j;
            const char* g;
            if (bi < 16) g = pA + (bi >> 2) * 32 * KDIM + (bi & 3) * 32;
            else {
                int b2 = bi - 16;
                g = pW + (b2 >> 2) * 32 * KDIM + (b2 & 3) * 32;
            }
            __builtin_amdgcn_global_load_lds(
                (const __attribute__((address_space(1))) void*)g,
                (__attribute__((address_space(3))) void*)(lds + bi * 1024),
                16, 0, 0);
        }
        __syncthreads();

#pragma unroll
        for (int s = 0; s < 4; ++s) {
            v4i av[2], wv[4];
#pragma unroll
            for (int mt = 0; mt < 2; ++mt) av[mt] = fA[(mt * 4 + s) * 64];
#pragma unroll
            for (int nt = 0; nt < 4; ++nt) wv[nt] = fW[(nt * 4 + s) * 64];
#pragma unroll
            for (int mt = 0; mt < 2; ++mt)
#pragma unroll
                for (int nt = 0; nt < 4; ++nt)
                    acc[mt][nt] = __builtin_amdgcn_mfma_i32_32x32x32_i8(
                        av[mt], wv[nt], acc[mt][nt], 0, 0, 0);
        }
        __syncthreads();
        pA += BKB; pW += BKB;
    }

    // Epilogue. C/D layout (32x32, HW-verified): col = lane&31,
    // row = (reg&3) + 8*(reg>>2) + 4*(lane>>5).
    const int cl = lane & 31;
    const int r0 = (lane >> 5) * 4;
#pragma unroll
    for (int mt = 0; mt < 2; ++mt) {
        const int rowbase = m0 + (mtb + mt) * 32 + r0;
#pragma unroll
        for (int nt = 0; nt < 4; ++nt) {
            const int col = n0 + (ntb + nt) * 32 + cl;
            const float bv = bias[col];
#pragma unroll
            for (int r = 0; r < 16; ++r) {
                const int row = rowbase + (r & 3) + 8 * (r >> 2);
                out[(size_t)row * OUTF + col] = (float)acc[mt][nt][r] + bv;
            }
        }
    }
}

extern "C" void kernel_launch(void* const* d_in, const int* in_sizes, int n_in,
                              void* d_out, int out_size, void* d_ws, size_t ws_size,
                              hipStream_t stream) {
    const int*   a_packed = (const int*)d_in[0];    // [8192, 512]
    const int*   w_packed = (const int*)d_in[1];    // [4096, 512]
    const float* bias     = (const float*)d_in[2];  // [4096]
    float*       out      = (float*)d_out;          // [8192, 4096]

    char* Ai8 = (char*)d_ws;                         // 32 MiB
    char* Wi8 = Ai8 + (size_t)BATCH * KDIM;          // 16 MiB

    const int npairs = (BATCH * 512 + OUTF * 512) / 2;   // 3,145,728
    unpack_kernel<<<npairs / 256, 256, 0, stream>>>(a_packed, w_packed, Ai8, Wi8);

    dim3 grid(OUTF / BN, BATCH / BM);   // (16, 64)
    bitgemm_mfma<<<grid, 256, 0, stream>>>(Ai8, Wi8, bias, out);
}

// Round 3
// 310.602 us; speedup vs baseline: 1.4371x; 1.4150x over previous
//
#include <hip/hip_runtime.h>
#include <stdint.h>

// BitLinear via i8 MFMA, round 3: blocked global layout so GEMM staging is
// fully contiguous.
//
// Unpack writes A/W as +/-1 int8 in MFMA-FRAGMENT-BLOCKED layout:
//   byte (m,k) -> ((g*32+c)*4096) + s*1024 + half*512 + r*16 + b
//   g=m>>5, r=m&31, c=k>>7, s=(k>>5)&3, half=(k>>4)&1, b=k&15
// Each 1 KB block = one wave fragment in lane order (lane = r + 32*half,
// 16 B/lane) == exactly global_load_lds's dest layout (base + lane*16).
//
// GEMM: block tile 128(M) x 256(N), 4 waves, wave-tile 64x128,
// v_mfma_i32_32x32x32_i8, BK=128 bytes, 48 x 1KB fragment blocks in LDS,
// every global_load_lds reads 1024 CONTIGUOUS bytes.

typedef int v4i  __attribute__((ext_vector_type(4)));
typedef int v16i __attribute__((ext_vector_type(16)));

#define BATCH 8192
#define OUTF  4096
#define KDIM  4096
#define BM    128
#define BN    256
#define BKB   128

// ---------------- unpack: packed bits -> +/-1 int8, blocked layout ----------
__device__ inline void expand8(uint32_t x, uint32_t& lo, uint32_t& hi) {
    lo = 0u; hi = 0u;
#pragma unroll
    for (int j = 0; j < 4; ++j) {
        lo |= ((((x >> j)       & 1u) * 2u - 1u) & 0xFFu) << (8 * j);
        hi |= ((((x >> (j + 4)) & 1u) * 2u - 1u) & 0xFFu) << (8 * j);
    }
}

// one thread: matrix (g,c,s,r) -> reads 4 packed int32 (32 bits = 32 k-bytes),
// writes two int4 (half=0 at idx, half=1 at idx+32).
__device__ inline void unpack_one(const int* __restrict__ src, int4* __restrict__ dst,
                                  int t) {
    const int r = t & 31;
    const int s = (t >> 5) & 3;
    const int c = (t >> 7) & 31;
    const int g = t >> 12;
    const int m = g * 32 + r;
    int4 v = ((const int4*)src)[m * 128 + c * 4 + s];   // 128 int4 per packed row
    uint32_t l0, h0, l1, h1, l2, h2, l3, h3;
    expand8((uint32_t)v.x, l0, h0);
    expand8((uint32_t)v.y, l1, h1);
    expand8((uint32_t)v.z, l2, h2);
    expand8((uint32_t)v.w, l3, h3);
    const int idx = (g * 32 + c) * 256 + s * 64 + r;
    int4 o0; o0.x = (int)l0; o0.y = (int)h0; o0.z = (int)l1; o0.w = (int)h1;
    int4 o1; o1.x = (int)l2; o1.y = (int)h2; o1.z = (int)l3; o1.w = (int)h3;
    dst[idx]      = o0;   // half 0
    dst[idx + 32] = o1;   // half 1
}

__global__ __launch_bounds__(256) void unpack_kernel(const int* __restrict__ a_packed,
                                                     const int* __restrict__ w_packed,
                                                     char* __restrict__ Ai8,
                                                     char* __restrict__ Wi8) {
    const int A_WORK = BATCH * 128;   // 1,048,576 threads
    const int W_WORK = OUTF * 128;    //   524,288 threads
    int t = blockIdx.x * 256 + threadIdx.x;
    if (t < A_WORK) {
        unpack_one(a_packed, (int4*)Ai8, t);
    } else {
        t -= A_WORK;
        if (t < W_WORK) unpack_one(w_packed, (int4*)Wi8, t);
    }
}

// ---------------- i8 MFMA GEMM (blocked inputs) ----------------
__global__ __launch_bounds__(256) void bitgemm_mfma(const char* __restrict__ A,
                                                    const char* __restrict__ W,
                                                    const float* __restrict__ bias,
                                                    float* __restrict__ out) {
    // 48 fragment blocks of 1 KB: A blocks 0..15 (mt*4+s), W blocks 16..47 (nt*4+s).
    __shared__ __attribute__((aligned(16))) char lds[48 * 1024];

    const int tid  = threadIdx.x;
    const int lane = tid & 63;
    const int w    = __builtin_amdgcn_readfirstlane(tid >> 6);
    const int m0   = blockIdx.y * BM;
    const int n0   = blockIdx.x * BN;

    // blocked: group stride = 32 chunks * 4096 B = 131072 B
    const char* pA = A + (size_t)blockIdx.y * 4 * 131072 + lane * 16;
    const char* pW = W + (size_t)blockIdx.x * 8 * 131072 + lane * 16;

    const int mtb = (w & 1) * 2;   // wave's A tile base (of 4)
    const int ntb = (w >> 1) * 4;  // wave's W tile base (of 8)

    v16i acc[2][4];
#pragma unroll
    for (int mt = 0; mt < 2; ++mt)
#pragma unroll
        for (int nt = 0; nt < 4; ++nt)
#pragma unroll
            for (int r = 0; r < 16; ++r) acc[mt][nt][r] = 0;

    const v4i* fA = (const v4i*)(lds) + mtb * 4 * 64 + lane;
    const v4i* fW = (const v4i*)(lds + 16 * 1024) + ntb * 4 * 64 + lane;

#pragma unroll 1
    for (int kc = 0; kc < KDIM; kc += BKB) {
        // wave w stages fragment blocks w*12 .. w*12+11; each is 1 KB contiguous.
#pragma unroll
        for (int j = 0; j < 12; ++j) {
            int bi = w * 12 + j;
            const char* g;
            if (bi < 16) g = pA + (bi >> 2) * 131072 + (bi & 3) * 1024;
            else {
                int b2 = bi - 16;
                g = pW + (b2 >> 2) * 131072 + (b2 & 3) * 1024;
            }
            __builtin_amdgcn_global_load_lds(
                (const __attribute__((address_space(1))) void*)g,
                (__attribute__((address_space(3))) void*)(lds + bi * 1024),
                16, 0, 0);
        }
        __syncthreads();

#pragma unroll
        for (int s = 0; s < 4; ++s) {
            v4i av[2], wv[4];
#pragma unroll
            for (int mt = 0; mt < 2; ++mt) av[mt] = fA[(mt * 4 + s) * 64];
#pragma unroll
            for (int nt = 0; nt < 4; ++nt) wv[nt] = fW[(nt * 4 + s) * 64];
#pragma unroll
            for (int mt = 0; mt < 2; ++mt)
#pragma unroll
                for (int nt = 0; nt < 4; ++nt)
                    acc[mt][nt] = __builtin_amdgcn_mfma_i32_32x32x32_i8(
                        av[mt], wv[nt], acc[mt][nt], 0, 0, 0);
        }
        __syncthreads();
        pA += 4096; pW += 4096;   // next 128-B k-chunk (one 4 KB group-chunk block)
    }

    // Epilogue. C/D layout (32x32, HW-verified): col=lane&31,
    // row=(reg&3)+8*(reg>>2)+4*(lane>>5).
    const int cl = lane & 31;
    const int r0 = (lane >> 5) * 4;
#pragma unroll
    for (int mt = 0; mt < 2; ++mt) {
        const int rowbase = m0 + (mtb + mt) * 32 + r0;
#pragma unroll
        for (int nt = 0; nt < 4; ++nt) {
            const int col = n0 + (ntb + nt) * 32 + cl;
            const float bv = bias[col];
#pragma unroll
            for (int r = 0; r < 16; ++r) {
                const int row = rowbase + (r & 3) + 8 * (r >> 2);
                out[(size_t)row * OUTF + col] = (float)acc[mt][nt][r] + bv;
            }
        }
    }
}

extern "C" void kernel_launch(void* const* d_in, const int* in_sizes, int n_in,
                              void* d_out, int out_size, void* d_ws, size_t ws_size,
                              hipStream_t stream) {
    const int*   a_packed = (const int*)d_in[0];    // [8192, 512]
    const int*   w_packed = (const int*)d_in[1];    // [4096, 512]
    const float* bias     = (const float*)d_in[2];  // [4096]
    float*       out      = (float*)d_out;          // [8192, 4096]

    char* Ai8 = (char*)d_ws;                         // 32 MiB blocked
    char* Wi8 = Ai8 + (size_t)BATCH * KDIM;          // 16 MiB blocked

    const int total = BATCH * 128 + OUTF * 128;      // 1,572,864 threads
    unpack_kernel<<<total / 256, 256, 0, stream>>>(a_packed, w_packed, Ai8, Wi8);

    dim3 grid(OUTF / BN, BATCH / BM);   // (16, 64)
    bitgemm_mfma<<<grid, 256, 0, stream>>>(Ai8, Wi8, bias, out);
}

// Round 4
// 282.072 us; speedup vs baseline: 1.5824x; 1.1011x over previous
//
#include <hip/hip_runtime.h>
#include <stdint.h>

// BitLinear via i8 MFMA, round 4: same blocked-fragment design as round 3,
// plus __launch_bounds__(256, 2) to force total regs (arch + acc, unified
// file on gfx950) <= 256 so 2 waves/SIMD (= 2 blocks/CU) are resident.
// Round 3 sat at 284 regs -> 1 wave/SIMD -> zero latency hiding.
//
// Unpack writes A/W as +/-1 int8 in MFMA-FRAGMENT-BLOCKED layout:
//   byte (m,k) -> ((g*32+c)*4096) + s*1024 + half*512 + r*16 + b
//   g=m>>5, r=m&31, c=k>>7, s=(k>>5)&3, half=(k>>4)&1, b=k&15
// Each 1 KB block = one wave fragment in lane order (lane = r + 32*half,
// 16 B/lane) == exactly global_load_lds's dest layout (base + lane*16).
//
// GEMM: block tile 128(M) x 256(N), 4 waves, wave-tile 64x128,
// v_mfma_i32_32x32x32_i8, BK=128 bytes, 48 x 1KB fragment blocks in LDS,
// every global_load_lds reads 1024 CONTIGUOUS bytes.

typedef int v4i  __attribute__((ext_vector_type(4)));
typedef int v16i __attribute__((ext_vector_type(16)));

#define BATCH 8192
#define OUTF  4096
#define KDIM  4096
#define BM    128
#define BN    256
#define BKB   128

// ---------------- unpack: packed bits -> +/-1 int8, blocked layout ----------
__device__ inline void expand8(uint32_t x, uint32_t& lo, uint32_t& hi) {
    lo = 0u; hi = 0u;
#pragma unroll
    for (int j = 0; j < 4; ++j) {
        lo |= ((((x >> j)       & 1u) * 2u - 1u) & 0xFFu) << (8 * j);
        hi |= ((((x >> (j + 4)) & 1u) * 2u - 1u) & 0xFFu) << (8 * j);
    }
}

__device__ inline void unpack_one(const int* __restrict__ src, int4* __restrict__ dst,
                                  int t) {
    const int r = t & 31;
    const int s = (t >> 5) & 3;
    const int c = (t >> 7) & 31;
    const int g = t >> 12;
    const int m = g * 32 + r;
    int4 v = ((const int4*)src)[m * 128 + c * 4 + s];
    uint32_t l0, h0, l1, h1, l2, h2, l3, h3;
    expand8((uint32_t)v.x, l0, h0);
    expand8((uint32_t)v.y, l1, h1);
    expand8((uint32_t)v.z, l2, h2);
    expand8((uint32_t)v.w, l3, h3);
    const int idx = (g * 32 + c) * 256 + s * 64 + r;
    int4 o0; o0.x = (int)l0; o0.y = (int)h0; o0.z = (int)l1; o0.w = (int)h1;
    int4 o1; o1.x = (int)l2; o1.y = (int)h2; o1.z = (int)l3; o1.w = (int)h3;
    dst[idx]      = o0;   // half 0
    dst[idx + 32] = o1;   // half 1
}

__global__ __launch_bounds__(256) void unpack_kernel(const int* __restrict__ a_packed,
                                                     const int* __restrict__ w_packed,
                                                     char* __restrict__ Ai8,
                                                     char* __restrict__ Wi8) {
    const int A_WORK = BATCH * 128;
    const int W_WORK = OUTF * 128;
    int t = blockIdx.x * 256 + threadIdx.x;
    if (t < A_WORK) {
        unpack_one(a_packed, (int4*)Ai8, t);
    } else {
        t -= A_WORK;
        if (t < W_WORK) unpack_one(w_packed, (int4*)Wi8, t);
    }
}

// ---------------- i8 MFMA GEMM (blocked inputs) ----------------
__global__ __launch_bounds__(256, 2) void bitgemm_mfma(const char* __restrict__ A,
                                                       const char* __restrict__ W,
                                                       const float* __restrict__ bias,
                                                       float* __restrict__ out) {
    // 48 fragment blocks of 1 KB: A blocks 0..15 (mt*4+s), W blocks 16..47 (nt*4+s).
    __shared__ __attribute__((aligned(16))) char lds[48 * 1024];

    const int tid  = threadIdx.x;
    const int lane = tid & 63;
    const int w    = __builtin_amdgcn_readfirstlane(tid >> 6);
    const int m0   = blockIdx.y * BM;
    const int n0   = blockIdx.x * BN;

    // blocked: group (32 rows) stride = 32 chunks * 4096 B = 131072 B
    const char* pA = A + (size_t)blockIdx.y * 4 * 131072 + lane * 16;
    const char* pW = W + (size_t)blockIdx.x * 8 * 131072 + lane * 16;

    const int mtb = (w & 1) * 2;   // wave's A tile base (of 4)
    const int ntb = (w >> 1) * 4;  // wave's W tile base (of 8)

    v16i acc[2][4];
#pragma unroll
    for (int mt = 0; mt < 2; ++mt)
#pragma unroll
        for (int nt = 0; nt < 4; ++nt)
#pragma unroll
            for (int r = 0; r < 16; ++r) acc[mt][nt][r] = 0;

    const v4i* fA = (const v4i*)(lds) + mtb * 4 * 64 + lane;
    const v4i* fW = (const v4i*)(lds + 16 * 1024) + ntb * 4 * 64 + lane;

#pragma unroll 1
    for (int kc = 0; kc < KDIM; kc += BKB) {
        // wave w stages fragment blocks w*12 .. w*12+11; each 1 KB contiguous.
#pragma unroll
        for (int j = 0; j < 12; ++j) {
            int bi = w * 12 + j;
            const char* g;
            if (bi < 16) g = pA + (bi >> 2) * 131072 + (bi & 3) * 1024;
            else {
                int b2 = bi - 16;
                g = pW + (b2 >> 2) * 131072 + (b2 & 3) * 1024;
            }
            __builtin_amdgcn_global_load_lds(
                (const __attribute__((address_space(1))) void*)g,
                (__attribute__((address_space(3))) void*)(lds + bi * 1024),
                16, 0, 0);
        }
        __syncthreads();

#pragma unroll
        for (int s = 0; s < 4; ++s) {
            v4i av[2], wv[4];
#pragma unroll
            for (int mt = 0; mt < 2; ++mt) av[mt] = fA[(mt * 4 + s) * 64];
#pragma unroll
            for (int nt = 0; nt < 4; ++nt) wv[nt] = fW[(nt * 4 + s) * 64];
#pragma unroll
            for (int mt = 0; mt < 2; ++mt)
#pragma unroll
                for (int nt = 0; nt < 4; ++nt)
                    acc[mt][nt] = __builtin_amdgcn_mfma_i32_32x32x32_i8(
                        av[mt], wv[nt], acc[mt][nt], 0, 0, 0);
        }
        __syncthreads();
        pA += 4096; pW += 4096;   // next 128-B k-chunk
    }

    // Epilogue. C/D layout (32x32, HW-verified): col=lane&31,
    // row=(reg&3)+8*(reg>>2)+4*(lane>>5).
    const int cl = lane & 31;
    const int r0 = (lane >> 5) * 4;
#pragma unroll
    for (int mt = 0; mt < 2; ++mt) {
        const int rowbase = m0 + (mtb + mt) * 32 + r0;
#pragma unroll
        for (int nt = 0; nt < 4; ++nt) {
            const int col = n0 + (ntb + nt) * 32 + cl;
            const float bv = bias[col];
#pragma unroll
            for (int r = 0; r < 16; ++r) {
                const int row = rowbase + (r & 3) + 8 * (r >> 2);
                out[(size_t)row * OUTF + col] = (float)acc[mt][nt][r] + bv;
            }
        }
    }
}

extern "C" void kernel_launch(void* const* d_in, const int* in_sizes, int n_in,
                              void* d_out, int out_size, void* d_ws, size_t ws_size,
                              hipStream_t stream) {
    const int*   a_packed = (const int*)d_in[0];    // [8192, 512]
    const int*   w_packed = (const int*)d_in[1];    // [4096, 512]
    const float* bias     = (const float*)d_in[2];  // [4096]
    float*       out      = (float*)d_out;          // [8192, 4096]

    char* Ai8 = (char*)d_ws;                         // 32 MiB blocked
    char* Wi8 = Ai8 + (size_t)BATCH * KDIM;          // 16 MiB blocked

    const int total = BATCH * 128 + OUTF * 128;      // 1,572,864 threads
    unpack_kernel<<<total / 256, 256, 0, stream>>>(a_packed, w_packed, Ai8, Wi8);

    dim3 grid(OUTF / BN, BATCH / BM);   // (16, 64)
    bitgemm_mfma<<<grid, 256, 0, stream>>>(Ai8, Wi8, bias, out);
}